// Round 1
// baseline (5090.471 us; speedup 1.0000x reference)
//
#include <hip/hip_runtime.h>
#include <math.h>

#define NB 8
#define NS 32
#define NN 2048
#define ND 64
#define NH 128
#define NE 32768
#define NT (NB*NN)
#define LN_EPS 1e-5f
#define ROWS 16

// ---------------- CSR build (topology is time-invariant) ----------------

__global__ void k_count(const int* __restrict__ dst, int* __restrict__ deg) {
  int e = blockIdx.x * blockDim.x + threadIdx.x;
  if (e < NE) atomicAdd(&deg[dst[e]], 1);
}

__global__ void k_scan(const int* __restrict__ deg, int* __restrict__ row_start,
                       float* __restrict__ dinv) {
  if (threadIdx.x == 0) {
    int acc = 0;
    for (int n = 0; n < NN; n++) { row_start[n] = acc; acc += deg[n]; }
    row_start[NN] = acc;
  }
  for (int n = threadIdx.x; n < NN; n += blockDim.x) {
    dinv[n] = rsqrtf((float)(deg[n] + 1));  // +1 self loop; always > 0
  }
}

__global__ void k_scatter(const int* __restrict__ src, const int* __restrict__ dst,
                          const int* __restrict__ row_start, int* __restrict__ cursor,
                          int* __restrict__ csr_src) {
  int e = blockIdx.x * blockDim.x + threadIdx.x;
  if (e < NE) {
    int d = dst[e];
    int pos = atomicAdd(&cursor[d], 1);
    csr_src[row_start[d] + pos] = src[e];
  }
}

// ---------------- dense projections (fp32 vector) ----------------
// Tz/Tr = x_t @ Wz[:64] + h @ Wz[64:]   (bias added after aggregation)

__global__ __launch_bounds__(128)
void k_proj_zr(const float* __restrict__ x, const float* __restrict__ h,
               const float* __restrict__ Wz, const float* __restrict__ Wr,
               float* __restrict__ Tz, float* __restrict__ Tr, int s) {
  __shared__ float lx[ROWS * ND];
  __shared__ float lh[ROWS * NH];
  int f = threadIdx.x;
  int t0 = blockIdx.x * ROWS;
  for (int i = f; i < ROWS * ND; i += 128) {
    int r = i >> 6, d = i & 63;
    int t = t0 + r; int b = t / NN; int n = t - b * NN;
    lx[i] = x[((b * NS + s) * NN + n) * ND + d];
  }
  for (int i = f; i < ROWS * NH; i += 128) {
    int r = i >> 7, c = i & 127;
    lh[i] = h[(t0 + r) * NH + c];
  }
  __syncthreads();
  float az[ROWS], ar[ROWS];
#pragma unroll
  for (int r = 0; r < ROWS; r++) { az[r] = 0.f; ar[r] = 0.f; }
  for (int k = 0; k < ND; k++) {
    float wz = Wz[k * NH + f], wr = Wr[k * NH + f];
#pragma unroll
    for (int r = 0; r < ROWS; r++) {
      float xv = lx[r * ND + k];
      az[r] = fmaf(xv, wz, az[r]);
      ar[r] = fmaf(xv, wr, ar[r]);
    }
  }
  for (int k = 0; k < NH; k++) {
    float wz = Wz[(ND + k) * NH + f], wr = Wr[(ND + k) * NH + f];
#pragma unroll
    for (int r = 0; r < ROWS; r++) {
      float hv = lh[r * NH + k];
      az[r] = fmaf(hv, wz, az[r]);
      ar[r] = fmaf(hv, wr, ar[r]);
    }
  }
#pragma unroll
  for (int r = 0; r < ROWS; r++) {
    Tz[(t0 + r) * NH + f] = az[r];
    Tr[(t0 + r) * NH + f] = ar[r];
  }
}

__global__ __launch_bounds__(128)
void k_proj_c(const float* __restrict__ x, const float* __restrict__ rh,
              const float* __restrict__ Wc, float* __restrict__ Tc, int s) {
  __shared__ float lx[ROWS * ND];
  __shared__ float lh[ROWS * NH];
  int f = threadIdx.x;
  int t0 = blockIdx.x * ROWS;
  for (int i = f; i < ROWS * ND; i += 128) {
    int r = i >> 6, d = i & 63;
    int t = t0 + r; int b = t / NN; int n = t - b * NN;
    lx[i] = x[((b * NS + s) * NN + n) * ND + d];
  }
  for (int i = f; i < ROWS * NH; i += 128) {
    int r = i >> 7, c = i & 127;
    lh[i] = rh[(t0 + r) * NH + c];
  }
  __syncthreads();
  float ac[ROWS];
#pragma unroll
  for (int r = 0; r < ROWS; r++) ac[r] = 0.f;
  for (int k = 0; k < ND; k++) {
    float wc = Wc[k * NH + f];
#pragma unroll
    for (int r = 0; r < ROWS; r++) ac[r] = fmaf(lx[r * ND + k], wc, ac[r]);
  }
  for (int k = 0; k < NH; k++) {
    float wc = Wc[(ND + k) * NH + f];
#pragma unroll
    for (int r = 0; r < ROWS; r++) ac[r] = fmaf(lh[r * NH + k], wc, ac[r]);
  }
#pragma unroll
  for (int r = 0; r < ROWS; r++) Tc[(t0 + r) * NH + f] = ac[r];
}

// ---------------- aggregation + gates ----------------
// out[t] = dinv[n] * ( sum_{e: dst=n} dinv[src]*T[b*N+src] + dinv[n]*T[t] ) + bias

__global__ __launch_bounds__(128)
void k_agg_zr(const float* __restrict__ Tz, const float* __restrict__ Tr,
              const float* __restrict__ h,
              const int* __restrict__ row_start, const int* __restrict__ csr_src,
              const float* __restrict__ dinv,
              const float* __restrict__ bz, const float* __restrict__ br,
              float* __restrict__ z, float* __restrict__ rh) {
  int t = blockIdx.x;
  int f = threadIdx.x;
  int b = t / NN, n = t - b * NN;
  int base = b * NN;
  float dn = dinv[n];
  float az = dn * Tz[t * NH + f];
  float ar = dn * Tr[t * NH + f];
  int k0 = row_start[n], k1 = row_start[n + 1];
  for (int k = k0; k < k1; k++) {
    int sn = csr_src[k];
    float w = dinv[sn];
    int idx = (base + sn) * NH + f;
    az = fmaf(w, Tz[idx], az);
    ar = fmaf(w, Tr[idx], ar);
  }
  float gz = dn * az + bz[f];
  float gr = dn * ar + br[f];
  float zv = 1.f / (1.f + __expf(-gz));
  float rv = 1.f / (1.f + __expf(-gr));
  z[t * NH + f] = zv;
  rh[t * NH + f] = rv * h[t * NH + f];
}

__global__ __launch_bounds__(128)
void k_agg_c(const float* __restrict__ Tc, const float* __restrict__ z,
             const int* __restrict__ row_start, const int* __restrict__ csr_src,
             const float* __restrict__ dinv, const float* __restrict__ bc,
             const float* __restrict__ gamma, const float* __restrict__ beta,
             float* __restrict__ h) {
  int t = blockIdx.x;
  int f = threadIdx.x;
  int b = t / NN, n = t - b * NN;
  int base = b * NN;
  float dn = dinv[n];
  float ac = dn * Tc[t * NH + f];
  int k0 = row_start[n], k1 = row_start[n + 1];
  for (int k = k0; k < k1; k++) {
    int sn = csr_src[k];
    ac = fmaf(dinv[sn], Tc[(base + sn) * NH + f], ac);
  }
  float gc = dn * ac + bc[f];
  // overflow-safe tanh
  float ea = __expf(-2.f * fabsf(gc));
  float th = (1.f - ea) / (1.f + ea);
  float cand = copysignf(th, gc);
  float zv = z[t * NH + f];
  float u = (1.f - zv) * h[t * NH + f] + zv * cand;
  // LayerNorm across 128 threads (2 waves)
  float sum = u, sq = u * u;
#pragma unroll
  for (int o = 1; o <= 32; o <<= 1) {
    sum += __shfl_xor(sum, o, 64);
    sq  += __shfl_xor(sq, o, 64);
  }
  __shared__ float ls[2], lq[2];
  int wid = f >> 6;
  if ((f & 63) == 0) { ls[wid] = sum; lq[wid] = sq; }
  __syncthreads();
  float tot = ls[0] + ls[1];
  float totq = lq[0] + lq[1];
  float mu = tot * (1.f / NH);
  float var = totq * (1.f / NH) - mu * mu;
  float inv = rsqrtf(var + LN_EPS);
  h[t * NH + f] = (u - mu) * inv * gamma[f] + beta[f];
}

__global__ void k_pool(const float* __restrict__ h, float* __restrict__ out) {
  int b = blockIdx.x, f = threadIdx.x;
  float acc = 0.f;
  for (int n = 0; n < NN; n++) acc += h[(b * NN + n) * NH + f];
  out[b * NH + f] = acc * (1.f / NN);
}

// ---------------- host ----------------

extern "C" void kernel_launch(void* const* d_in, const int* in_sizes, int n_in,
                              void* d_out, int out_size, void* d_ws, size_t ws_size,
                              hipStream_t stream) {
  const float* x     = (const float*)d_in[0];
  const int*   ei    = (const int*)d_in[1];
  const float* Wz    = (const float*)d_in[3];
  const float* bz    = (const float*)d_in[4];
  const float* Wr    = (const float*)d_in[5];
  const float* br    = (const float*)d_in[6];
  const float* Wc    = (const float*)d_in[7];
  const float* bc    = (const float*)d_in[8];
  const float* gamma = (const float*)d_in[9];
  const float* beta  = (const float*)d_in[10];
  float* out = (float*)d_out;

  char* ws = (char*)d_ws;
  size_t off = 0;
  auto alloc = [&](size_t bytes) {
    void* p = ws + off;
    off = (off + bytes + 255) & ~(size_t)255;
    return p;
  };
  float* h    = (float*)alloc((size_t)NT * NH * 4);
  float* z    = (float*)alloc((size_t)NT * NH * 4);
  float* rh   = (float*)alloc((size_t)NT * NH * 4);
  float* Tz   = (float*)alloc((size_t)NT * NH * 4);
  float* Tr   = (float*)alloc((size_t)NT * NH * 4);
  float* Tc   = (float*)alloc((size_t)NT * NH * 4);
  float* dinv = (float*)alloc(NN * 4);
  int* deg       = (int*)alloc(NN * 4);
  int* row_start = (int*)alloc((NN + 1) * 4);
  int* cursor    = (int*)alloc(NN * 4);
  int* csr_src   = (int*)alloc(NE * 4);

  const int* e_src = ei;
  const int* e_dst = ei + NE;

  hipMemsetAsync(h, 0, (size_t)NT * NH * 4, stream);
  hipMemsetAsync(deg, 0, NN * 4, stream);
  hipMemsetAsync(cursor, 0, NN * 4, stream);

  k_count<<<NE / 256, 256, 0, stream>>>(e_dst, deg);
  k_scan<<<1, 256, 0, stream>>>(deg, row_start, dinv);
  k_scatter<<<NE / 256, 256, 0, stream>>>(e_src, e_dst, row_start, cursor, csr_src);

  for (int s = 0; s < NS; s++) {
    k_proj_zr<<<NT / ROWS, 128, 0, stream>>>(x, h, Wz, Wr, Tz, Tr, s);
    k_agg_zr<<<NT, 128, 0, stream>>>(Tz, Tr, h, row_start, csr_src, dinv, bz, br, z, rh);
    k_proj_c<<<NT / ROWS, 128, 0, stream>>>(x, rh, Wc, Tc, s);
    k_agg_c<<<NT, 128, 0, stream>>>(Tc, z, row_start, csr_src, dinv, bc, gamma, beta, h);
  }
  k_pool<<<NB, NH, 0, stream>>>(h, out);
}

// Round 2
// 3617.292 us; speedup vs baseline: 1.4073x; 1.4073x over previous
//
#include <hip/hip_runtime.h>
#include <math.h>

#define NB 8
#define NS 32
#define NN 2048
#define ND 64
#define NH 128
#define NE 32768
#define NT (NB*NN)
#define LN_EPS 1e-5f

typedef __attribute__((ext_vector_type(8))) short short8v;
typedef __attribute__((ext_vector_type(4))) float f32x4;

static __device__ inline unsigned short f2bf(float f) {
  union { float f; unsigned int u; } v; v.f = f;
  unsigned int r = v.u + 0x7fffu + ((v.u >> 16) & 1u);
  return (unsigned short)(r >> 16);
}

// ---------------- CSR build (topology is time-invariant) ----------------

__global__ void k_count(const int* __restrict__ dst, int* __restrict__ deg) {
  int e = blockIdx.x * blockDim.x + threadIdx.x;
  if (e < NE) atomicAdd(&deg[dst[e]], 1);
}

__global__ void k_scan(const int* __restrict__ deg, int* __restrict__ row_start,
                       float* __restrict__ dinv) {
  if (threadIdx.x == 0) {
    int acc = 0;
    for (int n = 0; n < NN; n++) { row_start[n] = acc; acc += deg[n]; }
    row_start[NN] = acc;
  }
  for (int n = threadIdx.x; n < NN; n += blockDim.x) {
    dinv[n] = rsqrtf((float)(deg[n] + 1));  // +1 self loop; always > 0
  }
}

__global__ void k_scatter(const int* __restrict__ src, const int* __restrict__ dst,
                          const int* __restrict__ row_start, int* __restrict__ cursor,
                          int* __restrict__ csr_src) {
  int e = blockIdx.x * blockDim.x + threadIdx.x;
  if (e < NE) {
    int d = dst[e];
    int pos = atomicAdd(&cursor[d], 1);
    csr_src[row_start[d] + pos] = src[e];
  }
}

// ---------------- weight transpose + bf16 convert (once) ----------------
// Wt_zr[col][k]: col<128 -> Wz[:,col], col>=128 -> Wr[:,col-128].  Wt_c[col][k] = Wc[:,col].

__global__ void k_wcvt(const float* __restrict__ Wz, const float* __restrict__ Wr,
                       const float* __restrict__ Wc,
                       unsigned short* __restrict__ Wt_zr, unsigned short* __restrict__ Wt_c) {
  int col = blockIdx.x;   // 0..255
  int k = threadIdx.x;    // 0..191
  float v = (col < 128) ? Wz[k * 128 + col] : Wr[k * 128 + (col - 128)];
  Wt_zr[(size_t)col * 192 + k] = f2bf(v);
  if (col < 128) Wt_c[(size_t)col * 192 + k] = f2bf(Wc[k * 128 + col]);
}

// ---------------- Xa = A_hat @ x_s for ALL steps (fully parallel, once) ----

__global__ __launch_bounds__(256)
void k_aggX(const float* __restrict__ x, const int* __restrict__ row_start,
            const int* __restrict__ csr_src, const float* __restrict__ dinv,
            unsigned short* __restrict__ Xa) {
  int rid = blockIdx.x * 4 + (threadIdx.x >> 6);  // (s,t) row id
  int d = threadIdx.x & 63;
  int s = rid >> 14;          // NT = 16384 rows per step
  int t = rid & 16383;
  int b = t >> 11, n = t & 2047;
  float dn = dinv[n];
  const float* xs = x + ((size_t)b * NS + s) * NN * ND;
  float a = dn * xs[(size_t)n * ND + d];
  int k0 = row_start[n], k1 = row_start[n + 1];
  for (int k = k0; k < k1; k++) {
    int sn = csr_src[k];
    a = fmaf(dinv[sn], xs[(size_t)sn * ND + d], a);
  }
  Xa[((size_t)s * NT + t) * ND + d] = f2bf(dn * a);
}

// ---------------- per-step: aggregate a [NT,128] fp32 field -> bf16 -------

__global__ __launch_bounds__(128)
void k_aggF(const float* __restrict__ v, const int* __restrict__ row_start,
            const int* __restrict__ csr_src, const float* __restrict__ dinv,
            unsigned short* __restrict__ out) {
  int t = blockIdx.x, f = threadIdx.x;
  int b = t >> 11, n = t & 2047;
  int base = b << 11;
  float dn = dinv[n];
  float a = dn * v[(size_t)t * NH + f];
  int k0 = row_start[n], k1 = row_start[n + 1];
  for (int k = k0; k < k1; k++) {
    int sn = csr_src[k];
    a = fmaf(dinv[sn], v[(size_t)(base + sn) * NH + f], a);
  }
  out[(size_t)t * NH + f] = f2bf(dn * a);
}

// ---------------- z/r gates: MFMA GEMM [Xa_s | ha] @ [Wz|Wr] + epilogue ----
// one wave per (mtile of 16 rows, 16-col tile of H); computes z AND r there.

__global__ __launch_bounds__(256)
void k_zr(const unsigned short* __restrict__ Xa, const unsigned short* __restrict__ ha,
          const unsigned short* __restrict__ Wt,   // [256][192]
          const float* __restrict__ h, const float* __restrict__ bz,
          const float* __restrict__ br,
          float* __restrict__ z, float* __restrict__ rh, int s) {
  int lane = threadIdx.x & 63;
  int gw = blockIdx.x * 4 + (threadIdx.x >> 6);
  int mt = gw >> 3, ft = gw & 7;
  int m0 = mt * 16, f0 = ft * 16;
  int ar = m0 + (lane & 15);
  int koff = (lane >> 4) * 8;
  const unsigned short* xa = Xa + ((size_t)s * NT + ar) * ND;
  const unsigned short* wz = Wt + (size_t)(f0 + (lane & 15)) * 192;
  const unsigned short* wr = wz + (size_t)128 * 192;
  f32x4 az = {0.f, 0.f, 0.f, 0.f};
  f32x4 ag = {0.f, 0.f, 0.f, 0.f};
#pragma unroll
  for (int kb = 0; kb < 6; kb++) {
    int k = kb * 32 + koff;
    short8v a = (kb < 2) ? *(const short8v*)(xa + k)
                         : *(const short8v*)(ha + (size_t)ar * NH + (k - 64));
    short8v bz8 = *(const short8v*)(wz + k);
    short8v br8 = *(const short8v*)(wr + k);
    az = __builtin_amdgcn_mfma_f32_16x16x32_bf16(a, bz8, az, 0, 0, 0);
    ag = __builtin_amdgcn_mfma_f32_16x16x32_bf16(a, br8, ag, 0, 0, 0);
  }
  int col = f0 + (lane & 15);
  int r0 = m0 + (lane >> 4) * 4;
  float bzc = bz[col], brc = br[col];
#pragma unroll
  for (int q = 0; q < 4; q++) {
    size_t idx = (size_t)(r0 + q) * NH + col;
    float gz = az[q] + bzc, gr = ag[q] + brc;
    float zv = 1.f / (1.f + __expf(-gz));
    float rv = 1.f / (1.f + __expf(-gr));
    z[idx] = zv;
    rh[idx] = rv * h[idx];
  }
}

// ---------------- cand GEMM + gate + fused LayerNorm ----------------------
// block = 4 waves = one mtile (16 rows); wave w owns 2 col-tiles; LN via LDS.

__global__ __launch_bounds__(256)
void k_c(const unsigned short* __restrict__ Xa, const unsigned short* __restrict__ rha,
         const unsigned short* __restrict__ Wt,   // [128][192]
         const float* __restrict__ z, const float* __restrict__ bc,
         const float* __restrict__ gamma, const float* __restrict__ beta,
         float* __restrict__ h, int s) {
  __shared__ float lsum[4][16], lsq[4][16];
  int lane = threadIdx.x & 63;
  int w = threadIdx.x >> 6;
  int m0 = blockIdx.x * 16;
  int ar = m0 + (lane & 15);
  int koff = (lane >> 4) * 8;
  const unsigned short* xa = Xa + ((size_t)s * NT + ar) * ND;
  f32x4 acc[2];
  acc[0] = (f32x4){0.f, 0.f, 0.f, 0.f};
  acc[1] = (f32x4){0.f, 0.f, 0.f, 0.f};
#pragma unroll
  for (int kb = 0; kb < 6; kb++) {
    int k = kb * 32 + koff;
    short8v a = (kb < 2) ? *(const short8v*)(xa + k)
                         : *(const short8v*)(rha + (size_t)ar * NH + (k - 64));
#pragma unroll
    for (int j = 0; j < 2; j++) {
      int col = (2 * w + j) * 16 + (lane & 15);
      short8v b = *(const short8v*)(Wt + (size_t)col * 192 + k);
      acc[j] = __builtin_amdgcn_mfma_f32_16x16x32_bf16(a, b, acc[j], 0, 0, 0);
    }
  }
  int r0 = m0 + (lane >> 4) * 4;
  float u[2][4];
  float psum[4] = {0.f, 0.f, 0.f, 0.f};
  float psq[4] = {0.f, 0.f, 0.f, 0.f};
#pragma unroll
  for (int j = 0; j < 2; j++) {
    int col = (2 * w + j) * 16 + (lane & 15);
    float bcc = bc[col];
#pragma unroll
    for (int q = 0; q < 4; q++) {
      size_t idx = (size_t)(r0 + q) * NH + col;
      float gc = acc[j][q] + bcc;
      float ea = __expf(-2.f * fabsf(gc));
      float th = (1.f - ea) / (1.f + ea);
      float cand = copysignf(th, gc);
      float zv = z[idx];
      float uu = (1.f - zv) * h[idx] + zv * cand;
      u[j][q] = uu;
      psum[q] += uu; psq[q] += uu * uu;
    }
  }
#pragma unroll
  for (int q = 0; q < 4; q++) {
    float s1 = psum[q], s2 = psq[q];
#pragma unroll
    for (int o = 1; o <= 8; o <<= 1) {
      s1 += __shfl_xor(s1, o, 64);
      s2 += __shfl_xor(s2, o, 64);
    }
    if ((lane & 15) == 0) {
      int row16 = (lane >> 4) * 4 + q;
      lsum[w][row16] = s1; lsq[w][row16] = s2;
    }
  }
  __syncthreads();
#pragma unroll
  for (int j = 0; j < 2; j++) {
    int col = (2 * w + j) * 16 + (lane & 15);
    float g = gamma[col], bt = beta[col];
#pragma unroll
    for (int q = 0; q < 4; q++) {
      int row16 = (lane >> 4) * 4 + q;
      float tot = lsum[0][row16] + lsum[1][row16] + lsum[2][row16] + lsum[3][row16];
      float totq = lsq[0][row16] + lsq[1][row16] + lsq[2][row16] + lsq[3][row16];
      float mu = tot * (1.f / NH);
      float var = totq * (1.f / NH) - mu * mu;
      float inv = rsqrtf(var + LN_EPS);
      h[(size_t)(r0 + q) * NH + col] = (u[j][q] - mu) * inv * g + bt;
    }
  }
}

// ---------------- pool ----------------------------------------------------

__global__ __launch_bounds__(128)
void k_pool(const float* __restrict__ h, float* __restrict__ out) {
  int b = blockIdx.x >> 4;
  int chunk = blockIdx.x & 15;
  int f = threadIdx.x;
  float acc = 0.f;
  int n0 = chunk * 128;
  for (int n = n0; n < n0 + 128; n++) acc += h[((size_t)b * NN + n) * NH + f];
  atomicAdd(&out[b * NH + f], acc * (1.f / NN));
}

// ---------------- host ----------------------------------------------------

extern "C" void kernel_launch(void* const* d_in, const int* in_sizes, int n_in,
                              void* d_out, int out_size, void* d_ws, size_t ws_size,
                              hipStream_t stream) {
  const float* x     = (const float*)d_in[0];
  const int*   ei    = (const int*)d_in[1];
  const float* Wz    = (const float*)d_in[3];
  const float* bz    = (const float*)d_in[4];
  const float* Wr    = (const float*)d_in[5];
  const float* br    = (const float*)d_in[6];
  const float* Wc    = (const float*)d_in[7];
  const float* bc    = (const float*)d_in[8];
  const float* gamma = (const float*)d_in[9];
  const float* beta  = (const float*)d_in[10];
  float* out = (float*)d_out;

  char* ws = (char*)d_ws;
  size_t off = 0;
  auto alloc = [&](size_t bytes) {
    void* p = ws + off;
    off = (off + bytes + 255) & ~(size_t)255;
    return p;
  };
  float* h   = (float*)alloc((size_t)NT * NH * 4);
  float* z   = (float*)alloc((size_t)NT * NH * 4);
  float* rh  = (float*)alloc((size_t)NT * NH * 4);
  unsigned short* ha    = (unsigned short*)alloc((size_t)NT * NH * 2);
  unsigned short* rha   = (unsigned short*)alloc((size_t)NT * NH * 2);
  unsigned short* Xa    = (unsigned short*)alloc((size_t)NS * NT * ND * 2);
  unsigned short* Wt_zr = (unsigned short*)alloc((size_t)256 * 192 * 2);
  unsigned short* Wt_c  = (unsigned short*)alloc((size_t)128 * 192 * 2);
  float* dinv = (float*)alloc(NN * 4);
  int* deg       = (int*)alloc(NN * 4);
  int* row_start = (int*)alloc((NN + 1) * 4);
  int* cursor    = (int*)alloc(NN * 4);
  int* csr_src   = (int*)alloc(NE * 4);

  const int* e_src = ei;
  const int* e_dst = ei + NE;

  hipMemsetAsync(h, 0, (size_t)NT * NH * 4, stream);
  hipMemsetAsync(deg, 0, NN * 4, stream);
  hipMemsetAsync(cursor, 0, NN * 4, stream);
  hipMemsetAsync(d_out, 0, (size_t)NB * NH * 4, stream);

  k_count<<<NE / 256, 256, 0, stream>>>(e_dst, deg);
  k_scan<<<1, 256, 0, stream>>>(deg, row_start, dinv);
  k_scatter<<<NE / 256, 256, 0, stream>>>(e_src, e_dst, row_start, cursor, csr_src);
  k_wcvt<<<256, 192, 0, stream>>>(Wz, Wr, Wc, Wt_zr, Wt_c);
  k_aggX<<<(NS * NT) / 4, 256, 0, stream>>>(x, row_start, csr_src, dinv, Xa);

  for (int s = 0; s < NS; s++) {
    k_aggF<<<NT, 128, 0, stream>>>(h, row_start, csr_src, dinv, ha);
    k_zr<<<2048, 256, 0, stream>>>(Xa, ha, Wt_zr, h, bz, br, z, rh, s);
    k_aggF<<<NT, 128, 0, stream>>>(rh, row_start, csr_src, dinv, rha);
    k_c<<<1024, 256, 0, stream>>>(Xa, rha, Wt_c, z, bc, gamma, beta, h, s);
  }
  k_pool<<<NB * 16, 128, 0, stream>>>(h, out);
}

// Round 3
// 2774.016 us; speedup vs baseline: 1.8351x; 1.3040x over previous
//
#include <hip/hip_runtime.h>
#include <math.h>

#define NB 8
#define NS 32
#define NN 2048
#define ND 64
#define NH 128
#define NE 32768
#define NT (NB*NN)
#define LN_EPS 1e-5f

typedef __attribute__((ext_vector_type(8))) short short8v;
typedef __attribute__((ext_vector_type(4))) float f32x4;

static __device__ inline unsigned short f2bf(float f) {
  union { float f; unsigned int u; } v; v.f = f;
  unsigned int r = v.u + 0x7fffu + ((v.u >> 16) & 1u);
  return (unsigned short)(r >> 16);
}

// ---------------- CSR build (topology is time-invariant) ----------------

__global__ void k_count(const int* __restrict__ dst, int* __restrict__ deg) {
  int e = blockIdx.x * blockDim.x + threadIdx.x;
  if (e < NE) atomicAdd(&deg[dst[e]], 1);
}

__global__ void k_scan(const int* __restrict__ deg, int* __restrict__ row_start,
                       float* __restrict__ dinv) {
  if (threadIdx.x == 0) {
    int acc = 0;
    for (int n = 0; n < NN; n++) { row_start[n] = acc; acc += deg[n]; }
    row_start[NN] = acc;
  }
  for (int n = threadIdx.x; n < NN; n += blockDim.x) {
    dinv[n] = rsqrtf((float)(deg[n] + 1));  // +1 self loop; always > 0
  }
}

__global__ void k_scatter(const int* __restrict__ src, const int* __restrict__ dst,
                          const int* __restrict__ row_start, int* __restrict__ cursor,
                          int* __restrict__ csr_src) {
  int e = blockIdx.x * blockDim.x + threadIdx.x;
  if (e < NE) {
    int d = dst[e];
    int pos = atomicAdd(&cursor[d], 1);
    csr_src[row_start[d] + pos] = src[e];
  }
}

// ---------------- weight transpose + bf16 convert (once) ----------------

__global__ void k_wcvt(const float* __restrict__ Wz, const float* __restrict__ Wr,
                       const float* __restrict__ Wc,
                       unsigned short* __restrict__ Wt_zr, unsigned short* __restrict__ Wt_c) {
  int col = blockIdx.x;   // 0..255
  int k = threadIdx.x;    // 0..191
  float v = (col < 128) ? Wz[k * 128 + col] : Wr[k * 128 + (col - 128)];
  Wt_zr[(size_t)col * 192 + k] = f2bf(v);
  if (col < 128) Wt_c[(size_t)col * 192 + k] = f2bf(Wc[k * 128 + col]);
}

// ---------------- Xa = A_hat @ x_s for ALL steps (once) -------------------
// XCD-chunked swizzle keeps each (s,b) 512KB slab on ONE XCD's L2.
// Wave-parallel index fetch + shfl broadcast removes the per-neighbor
// dependent index-load chain.

__global__ __launch_bounds__(256)
void k_aggX(const float* __restrict__ x, const int* __restrict__ row_start,
            const int* __restrict__ csr_src, const float* __restrict__ dinv,
            unsigned short* __restrict__ Xa) {
  const int NBLK = (NS * NT) / 4;               // 131072
  int bid = blockIdx.x;
  int bs = (bid & 7) * (NBLK / 8) + (bid >> 3); // chunk per XCD
  int rid = bs * 4 + (threadIdx.x >> 6);
  int lane = threadIdx.x & 63;
  int s = rid >> 14;
  int t = rid & 16383;
  int b = t >> 11, n = t & 2047;
  float dn = dinv[n];
  const float* xs = x + ((size_t)b * NS + s) * (NN * ND);
  float a = dn * xs[n * ND + lane];
  int k0 = row_start[n], k1 = row_start[n + 1];
  for (int kb = k0; kb < k1; kb += 64) {
    int m = k1 - kb; if (m > 64) m = 64;
    int idx = 0; float wv = 0.f;
    if (lane < m) { idx = csr_src[kb + lane]; wv = dinv[idx]; }
    for (int k = 0; k < m; k++) {
      int sn = __shfl(idx, k, 64);
      float w = __shfl(wv, k, 64);
      a = fmaf(w, xs[sn * ND + lane], a);
    }
  }
  Xa[((size_t)s * NT + t) * ND + lane] = f2bf(dn * a);
}

// ---------------- per-step: aggregate a [NT,128] fp32 field -> bf16 -------
// Swizzle: batch b slab (1MB) pinned to XCD b.

__global__ __launch_bounds__(128)
void k_aggF(const float* __restrict__ v, const int* __restrict__ row_start,
            const int* __restrict__ csr_src, const float* __restrict__ dinv,
            unsigned short* __restrict__ out) {
  int bid = blockIdx.x;
  int t = ((bid & 7) << 11) | (bid >> 3);
  int f = threadIdx.x;
  int lane = f & 63;
  int b = t >> 11, n = t & 2047;
  int base = b << 11;
  float dn = dinv[n];
  const float* vb = v + (size_t)base * NH;
  float a = dn * vb[(size_t)n * NH + f];
  int k0 = row_start[n], k1 = row_start[n + 1];
  for (int kb = k0; kb < k1; kb += 64) {
    int m = k1 - kb; if (m > 64) m = 64;
    int idx = 0; float wv = 0.f;
    if (lane < m) { idx = csr_src[kb + lane]; wv = dinv[idx]; }
    for (int k = 0; k < m; k++) {
      int sn = __shfl(idx, k, 64);
      float w = __shfl(wv, k, 64);
      a = fmaf(w, vb[(size_t)sn * NH + f], a);
    }
  }
  out[(size_t)t * NH + f] = f2bf(dn * a);
}

// ---------------- z/r gates: MFMA GEMM [Xa_s | ha] @ [Wz|Wr] + epilogue ----

__global__ __launch_bounds__(256)
void k_zr(const unsigned short* __restrict__ Xa, const unsigned short* __restrict__ ha,
          const unsigned short* __restrict__ Wt,   // [256][192]
          const float* __restrict__ h, const float* __restrict__ bz,
          const float* __restrict__ br,
          float* __restrict__ z, float* __restrict__ rh, int s) {
  int lane = threadIdx.x & 63;
  int gw = blockIdx.x * 4 + (threadIdx.x >> 6);
  int mt = gw >> 3, ft = gw & 7;
  int m0 = mt * 16, f0 = ft * 16;
  int ar = m0 + (lane & 15);
  int koff = (lane >> 4) * 8;
  const unsigned short* xa = Xa + ((size_t)s * NT + ar) * ND;
  const unsigned short* wz = Wt + (size_t)(f0 + (lane & 15)) * 192;
  const unsigned short* wr = wz + (size_t)128 * 192;
  f32x4 az = {0.f, 0.f, 0.f, 0.f};
  f32x4 ag = {0.f, 0.f, 0.f, 0.f};
#pragma unroll
  for (int kb = 0; kb < 6; kb++) {
    int k = kb * 32 + koff;
    short8v a = (kb < 2) ? *(const short8v*)(xa + k)
                         : *(const short8v*)(ha + (size_t)ar * NH + (k - 64));
    short8v bz8 = *(const short8v*)(wz + k);
    short8v br8 = *(const short8v*)(wr + k);
    az = __builtin_amdgcn_mfma_f32_16x16x32_bf16(a, bz8, az, 0, 0, 0);
    ag = __builtin_amdgcn_mfma_f32_16x16x32_bf16(a, br8, ag, 0, 0, 0);
  }
  int col = f0 + (lane & 15);
  int r0 = m0 + (lane >> 4) * 4;
  float bzc = bz[col], brc = br[col];
#pragma unroll
  for (int q = 0; q < 4; q++) {
    size_t idx = (size_t)(r0 + q) * NH + col;
    float gz = az[q] + bzc, gr = ag[q] + brc;
    float zv = 1.f / (1.f + __expf(-gz));
    float rv = 1.f / (1.f + __expf(-gr));
    z[idx] = zv;
    rh[idx] = rv * h[idx];
  }
}

// ---------------- cand GEMM + gate + fused LayerNorm ----------------------

__global__ __launch_bounds__(256)
void k_c(const unsigned short* __restrict__ Xa, const unsigned short* __restrict__ rha,
         const unsigned short* __restrict__ Wt,   // [128][192]
         const float* __restrict__ z, const float* __restrict__ bc,
         const float* __restrict__ gamma, const float* __restrict__ beta,
         float* __restrict__ h, int s) {
  __shared__ float lsum[4][16], lsq[4][16];
  int lane = threadIdx.x & 63;
  int w = threadIdx.x >> 6;
  int m0 = blockIdx.x * 16;
  int ar = m0 + (lane & 15);
  int koff = (lane >> 4) * 8;
  const unsigned short* xa = Xa + ((size_t)s * NT + ar) * ND;
  f32x4 acc[2];
  acc[0] = (f32x4){0.f, 0.f, 0.f, 0.f};
  acc[1] = (f32x4){0.f, 0.f, 0.f, 0.f};
#pragma unroll
  for (int kb = 0; kb < 6; kb++) {
    int k = kb * 32 + koff;
    short8v a = (kb < 2) ? *(const short8v*)(xa + k)
                         : *(const short8v*)(rha + (size_t)ar * NH + (k - 64));
#pragma unroll
    for (int j = 0; j < 2; j++) {
      int col = (2 * w + j) * 16 + (lane & 15);
      short8v b = *(const short8v*)(Wt + (size_t)col * 192 + k);
      acc[j] = __builtin_amdgcn_mfma_f32_16x16x32_bf16(a, b, acc[j], 0, 0, 0);
    }
  }
  int r0 = m0 + (lane >> 4) * 4;
  float u[2][4];
  float psum[4] = {0.f, 0.f, 0.f, 0.f};
  float psq[4] = {0.f, 0.f, 0.f, 0.f};
#pragma unroll
  for (int j = 0; j < 2; j++) {
    int col = (2 * w + j) * 16 + (lane & 15);
    float bcc = bc[col];
#pragma unroll
    for (int q = 0; q < 4; q++) {
      size_t idx = (size_t)(r0 + q) * NH + col;
      float gc = acc[j][q] + bcc;
      float ea = __expf(-2.f * fabsf(gc));
      float th = (1.f - ea) / (1.f + ea);
      float cand = copysignf(th, gc);
      float zv = z[idx];
      float uu = (1.f - zv) * h[idx] + zv * cand;
      u[j][q] = uu;
      psum[q] += uu; psq[q] += uu * uu;
    }
  }
#pragma unroll
  for (int q = 0; q < 4; q++) {
    float s1 = psum[q], s2 = psq[q];
#pragma unroll
    for (int o = 1; o <= 8; o <<= 1) {
      s1 += __shfl_xor(s1, o, 64);
      s2 += __shfl_xor(s2, o, 64);
    }
    if ((lane & 15) == 0) {
      int row16 = (lane >> 4) * 4 + q;
      lsum[w][row16] = s1; lsq[w][row16] = s2;
    }
  }
  __syncthreads();
#pragma unroll
  for (int j = 0; j < 2; j++) {
    int col = (2 * w + j) * 16 + (lane & 15);
    float g = gamma[col], bt = beta[col];
#pragma unroll
    for (int q = 0; q < 4; q++) {
      int row16 = (lane >> 4) * 4 + q;
      float tot = lsum[0][row16] + lsum[1][row16] + lsum[2][row16] + lsum[3][row16];
      float totq = lsq[0][row16] + lsq[1][row16] + lsq[2][row16] + lsq[3][row16];
      float mu = tot * (1.f / NH);
      float var = totq * (1.f / NH) - mu * mu;
      float inv = rsqrtf(var + LN_EPS);
      h[(size_t)(r0 + q) * NH + col] = (u[j][q] - mu) * inv * g + bt;
    }
  }
}

// ---------------- pool ----------------------------------------------------

__global__ __launch_bounds__(128)
void k_pool(const float* __restrict__ h, float* __restrict__ out) {
  int b = blockIdx.x >> 4;
  int chunk = blockIdx.x & 15;
  int f = threadIdx.x;
  float acc = 0.f;
  int n0 = chunk * 128;
  for (int n = n0; n < n0 + 128; n++) acc += h[((size_t)b * NN + n) * NH + f];
  atomicAdd(&out[b * NH + f], acc * (1.f / NN));
}

// ---------------- host ----------------------------------------------------

extern "C" void kernel_launch(void* const* d_in, const int* in_sizes, int n_in,
                              void* d_out, int out_size, void* d_ws, size_t ws_size,
                              hipStream_t stream) {
  const float* x     = (const float*)d_in[0];
  const int*   ei    = (const int*)d_in[1];
  const float* Wz    = (const float*)d_in[3];
  const float* bz    = (const float*)d_in[4];
  const float* Wr    = (const float*)d_in[5];
  const float* br    = (const float*)d_in[6];
  const float* Wc    = (const float*)d_in[7];
  const float* bc    = (const float*)d_in[8];
  const float* gamma = (const float*)d_in[9];
  const float* beta  = (const float*)d_in[10];
  float* out = (float*)d_out;

  char* ws = (char*)d_ws;
  size_t off = 0;
  auto alloc = [&](size_t bytes) {
    void* p = ws + off;
    off = (off + bytes + 255) & ~(size_t)255;
    return p;
  };
  float* h   = (float*)alloc((size_t)NT * NH * 4);
  float* z   = (float*)alloc((size_t)NT * NH * 4);
  float* rh  = (float*)alloc((size_t)NT * NH * 4);
  unsigned short* ha    = (unsigned short*)alloc((size_t)NT * NH * 2);
  unsigned short* rha   = (unsigned short*)alloc((size_t)NT * NH * 2);
  unsigned short* Xa    = (unsigned short*)alloc((size_t)NS * NT * ND * 2);
  unsigned short* Wt_zr = (unsigned short*)alloc((size_t)256 * 192 * 2);
  unsigned short* Wt_c  = (unsigned short*)alloc((size_t)128 * 192 * 2);
  float* dinv = (float*)alloc(NN * 4);
  int* deg       = (int*)alloc(NN * 4);
  int* row_start = (int*)alloc((NN + 1) * 4);
  int* cursor    = (int*)alloc(NN * 4);
  int* csr_src   = (int*)alloc(NE * 4);

  const int* e_src = ei;
  const int* e_dst = ei + NE;

  hipMemsetAsync(h, 0, (size_t)NT * NH * 4, stream);
  hipMemsetAsync(deg, 0, NN * 4, stream);
  hipMemsetAsync(cursor, 0, NN * 4, stream);
  hipMemsetAsync(d_out, 0, (size_t)NB * NH * 4, stream);

  k_count<<<NE / 256, 256, 0, stream>>>(e_dst, deg);
  k_scan<<<1, 256, 0, stream>>>(deg, row_start, dinv);
  k_scatter<<<NE / 256, 256, 0, stream>>>(e_src, e_dst, row_start, cursor, csr_src);
  k_wcvt<<<256, 192, 0, stream>>>(Wz, Wr, Wc, Wt_zr, Wt_c);
  k_aggX<<<(NS * NT) / 4, 256, 0, stream>>>(x, row_start, csr_src, dinv, Xa);

  for (int s = 0; s < NS; s++) {
    k_aggF<<<NT, 128, 0, stream>>>(h, row_start, csr_src, dinv, ha);
    k_zr<<<2048, 256, 0, stream>>>(Xa, ha, Wt_zr, h, bz, br, z, rh, s);
    k_aggF<<<NT, 128, 0, stream>>>(rh, row_start, csr_src, dinv, rha);
    k_c<<<1024, 256, 0, stream>>>(Xa, rha, Wt_c, z, bc, gamma, beta, h, s);
  }
  k_pool<<<NB * 16, 128, 0, stream>>>(h, out);
}

// Round 4
// 1782.736 us; speedup vs baseline: 2.8554x; 1.5560x over previous
//
#include <hip/hip_runtime.h>
#include <math.h>

#define NB 8
#define NS 32
#define NN 2048
#define ND 64
#define NH 128
#define NE 32768
#define NT (NB*NN)
#define LN_EPS 1e-5f

typedef __attribute__((ext_vector_type(8))) short short8v;
typedef __attribute__((ext_vector_type(4))) float f32x4;
typedef __attribute__((ext_vector_type(4))) unsigned int u32x4;

static __device__ inline unsigned short f2bf(float f) {
  union { float f; unsigned int u; } v; v.f = f;
  unsigned int r = v.u + 0x7fffu + ((v.u >> 16) & 1u);
  return (unsigned short)(r >> 16);
}

// load 8 bf16 (16B) -> 8 fp32
static __device__ inline void bf8_to_f(const unsigned short* __restrict__ p, float* f) {
  u32x4 v = *(const u32x4*)p;
#pragma unroll
  for (int i = 0; i < 4; i++) {
    union { unsigned int u; float x; } lo, hi;
    lo.u = v[i] << 16; hi.u = v[i] & 0xFFFF0000u;
    f[2*i] = lo.x; f[2*i+1] = hi.x;
  }
}

// ---------------- CSR build (topology is time-invariant) ----------------

__global__ void k_count(const int* __restrict__ dst, int* __restrict__ deg) {
  int e = blockIdx.x * blockDim.x + threadIdx.x;
  if (e < NE) atomicAdd(&deg[dst[e]], 1);
}

__global__ void k_scan(const int* __restrict__ deg, int* __restrict__ row_start,
                       float* __restrict__ dinv) {
  if (threadIdx.x == 0) {
    int acc = 0;
    for (int n = 0; n < NN; n++) { row_start[n] = acc; acc += deg[n]; }
    row_start[NN] = acc;
  }
  for (int n = threadIdx.x; n < NN; n += blockDim.x) {
    dinv[n] = rsqrtf((float)(deg[n] + 1));
  }
}

__global__ void k_scatter(const int* __restrict__ src, const int* __restrict__ dst,
                          const int* __restrict__ row_start, int* __restrict__ cursor,
                          int* __restrict__ csr_src) {
  int e = blockIdx.x * blockDim.x + threadIdx.x;
  if (e < NE) {
    int d = dst[e];
    int pos = atomicAdd(&cursor[d], 1);
    csr_src[row_start[d] + pos] = src[e];
  }
}

// ---------------- weight transpose + bf16 convert (once) ----------------

__global__ void k_wcvt(const float* __restrict__ Wz, const float* __restrict__ Wr,
                       const float* __restrict__ Wc,
                       unsigned short* __restrict__ Wt_zr, unsigned short* __restrict__ Wt_c) {
  int col = blockIdx.x;   // 0..255
  int k = threadIdx.x;    // 0..191
  float v = (col < 128) ? Wz[k * 128 + col] : Wr[k * 128 + (col - 128)];
  Wt_zr[(size_t)col * 192 + k] = f2bf(v);
  if (col < 128) Wt_c[(size_t)col * 192 + k] = f2bf(Wc[k * 128 + col]);
}

// ---------------- transpose x -> xT[s][n][b][64] bf16 ----------------

__global__ __launch_bounds__(256)
void k_xT(const float* __restrict__ x, unsigned short* __restrict__ xT) {
  int blk = blockIdx.x;          // 16384 blocks: (s, group of 4 n)
  int s = blk >> 9;
  int n0 = (blk & 511) * 4;
  int t = threadIdx.x;
  int b = t >> 5;
  int d2 = (t & 31) * 2;
#pragma unroll
  for (int i = 0; i < 4; i++) {
    int n = n0 + i;
    const float2 v = *(const float2*)(x + (((size_t)b * NS + s) * NN + n) * ND + d2);
    unsigned int p = ((unsigned int)f2bf(v.y) << 16) | f2bf(v.x);
    *(unsigned int*)(xT + (((size_t)s * NN + n) * NB + b) * ND + d2) = p;
  }
}

// ---------------- Xa[s][n][b][64] = A_hat @ x (all steps, batch-amortized) --
// one wave per (s,n): 512 bf16 = 1KB row; s-slab (2MB) pinned per XCD.

__global__ __launch_bounds__(256)
void k_aggX2(const unsigned short* __restrict__ xT, const int* __restrict__ row_start,
             const int* __restrict__ csr_src, const float* __restrict__ dinv,
             unsigned short* __restrict__ Xa) {
  int bid = blockIdx.x;                     // 16384
  int bs = (bid & 7) * 2048 + (bid >> 3);   // XCD chunking: 4 s-slabs per XCD
  int rid = bs * 4 + (threadIdx.x >> 6);    // (s,n) id, 0..65535
  int lane = threadIdx.x & 63;
  int s = rid >> 11, n = rid & 2047;
  const unsigned short* xs = xT + (size_t)s * (NN * NB * ND);
  float dn = dinv[n];
  float acc[8], val[8];
  bf8_to_f(xs + (size_t)n * 512 + lane * 8, val);
#pragma unroll
  for (int i = 0; i < 8; i++) acc[i] = dn * val[i];
  int k0 = row_start[n], k1 = row_start[n + 1];
  for (int kb = k0; kb < k1; kb += 64) {
    int m = k1 - kb; if (m > 64) m = 64;
    int idx = 0; float wv = 0.f;
    if (lane < m) { idx = csr_src[kb + lane]; wv = dinv[idx]; }
    for (int k = 0; k < m; k++) {
      int sn = __shfl(idx, k, 64);
      float ww = __shfl(wv, k, 64);
      bf8_to_f(xs + (size_t)sn * 512 + lane * 8, val);
#pragma unroll
      for (int i = 0; i < 8; i++) acc[i] = fmaf(ww, val[i], acc[i]);
    }
  }
  unsigned int pk[4];
#pragma unroll
  for (int i = 0; i < 4; i++)
    pk[i] = ((unsigned int)f2bf(dn * acc[2*i+1]) << 16) | f2bf(dn * acc[2*i]);
  *(u32x4*)(Xa + (size_t)rid * 512 + lane * 8) = *(u32x4*)pk;
}

// ---------------- phase A: agg(hB) + [Xa|ha]@[Wz|Wr] + gates ----------------
// block = 256 thr, 2 nodes (16 GEMM rows = 2n x 8b). Row r: n=n0+(r>>3), b=r&7.

__global__ __launch_bounds__(256)
void k_zrF(const unsigned short* __restrict__ Xa, const unsigned short* __restrict__ hB,
           const float* __restrict__ h, const unsigned short* __restrict__ Wt,
           const int* __restrict__ row_start, const int* __restrict__ csr_src,
           const float* __restrict__ dinv,
           const float* __restrict__ bz, const float* __restrict__ br,
           float* __restrict__ z, unsigned short* __restrict__ rhB, int s) {
  __shared__ unsigned short ha[16 * 128];
  int tid = threadIdx.x;
  int lane = tid & 63;
  int w = tid >> 6;
  int n0 = blockIdx.x * 2;
  int j = w >> 1, half = w & 1;
  int n = n0 + j;
  // ---- gather: agg over hB rows (2KB each), this wave owns 512 of 1024 elems
  float dn = dinv[n];
  float acc[8], val[8];
  int foff = half * 512 + lane * 8;
  bf8_to_f(hB + (size_t)n * (NB * NH) + foff, val);
#pragma unroll
  for (int i = 0; i < 8; i++) acc[i] = dn * val[i];
  int k0 = row_start[n], k1 = row_start[n + 1];
  for (int kb = k0; kb < k1; kb += 64) {
    int m = k1 - kb; if (m > 64) m = 64;
    int idx = 0; float wv = 0.f;
    if (lane < m) { idx = csr_src[kb + lane]; wv = dinv[idx]; }
    for (int k = 0; k < m; k++) {
      int sn = __shfl(idx, k, 64);
      float ww = __shfl(wv, k, 64);
      bf8_to_f(hB + (size_t)sn * (NB * NH) + foff, val);
#pragma unroll
      for (int i = 0; i < 8; i++) acc[i] = fmaf(ww, val[i], acc[i]);
    }
  }
  {  // store to LDS [16][128] bf16, XOR-swizzled (T2)
    int row = j * 8 + (foff >> 7);
    int f = foff & 127;
    unsigned int pk[4];
#pragma unroll
    for (int i = 0; i < 4; i++)
      pk[i] = ((unsigned int)f2bf(dn * acc[2*i+1]) << 16) | f2bf(dn * acc[2*i]);
    int byte = (row * 256 + f * 2) ^ ((row & 7) << 4);
    *(u32x4*)((char*)ha + byte) = *(u32x4*)pk;
  }
  __syncthreads();
  // ---- GEMM rows 16 x cols 256 ([Wz|Wr]); wave w -> col-tiles 4w..4w+3
  int ar = lane & 15;
  int koff = (lane >> 4) * 8;
  short8v afr[6];
  const unsigned short* xrow =
      Xa + (((size_t)s * NN + n0 + (ar >> 3)) * NB + (ar & 7)) * ND;
  afr[0] = *(const short8v*)(xrow + koff);
  afr[1] = *(const short8v*)(xrow + 32 + koff);
#pragma unroll
  for (int kb = 2; kb < 6; kb++) {
    int kk = (kb - 2) * 32 + koff;
    int byte = (ar * 256 + kk * 2) ^ ((ar & 7) << 4);
    afr[kb] = *(const short8v*)((char*)ha + byte);
  }
  f32x4 cacc[4];
#pragma unroll
  for (int ct = 0; ct < 4; ct++) cacc[ct] = (f32x4){0.f, 0.f, 0.f, 0.f};
#pragma unroll
  for (int ct = 0; ct < 4; ct++) {
    const unsigned short* wcol = Wt + (size_t)((w * 4 + ct) * 16 + (lane & 15)) * 192;
#pragma unroll
    for (int kb = 0; kb < 6; kb++) {
      short8v bfr = *(const short8v*)(wcol + kb * 32 + koff);
      cacc[ct] = __builtin_amdgcn_mfma_f32_16x16x32_bf16(afr[kb], bfr, cacc[ct], 0, 0, 0);
    }
  }
  // ---- epilogue: col<128 -> z fp32 ; col>=128 -> rhB = sigmoid*h bf16
  int r0 = (lane >> 4) * 4;
#pragma unroll
  for (int ct = 0; ct < 4; ct++) {
    int col = (w * 4 + ct) * 16 + (lane & 15);
    int isz = (col < 128);
    int f = isz ? col : col - 128;
    float bias = isz ? bz[f] : br[f];
#pragma unroll
    for (int q = 0; q < 4; q++) {
      int r = r0 + q;
      size_t gidx = (((size_t)(n0 + (r >> 3))) * NB + (r & 7)) * NH + f;
      float g = cacc[ct][q] + bias;
      float sg = 1.f / (1.f + __expf(-g));
      if (isz) z[gidx] = sg;
      else rhB[gidx] = f2bf(sg * h[gidx]);
    }
  }
}

// ---------------- phase B: agg(rhB) + @Wc + tanh + gate + LN ----------------

__global__ __launch_bounds__(256)
void k_cF(const unsigned short* __restrict__ Xa, const unsigned short* __restrict__ rhB,
          const float* __restrict__ z, const unsigned short* __restrict__ Wt,
          const int* __restrict__ row_start, const int* __restrict__ csr_src,
          const float* __restrict__ dinv, const float* __restrict__ bc,
          const float* __restrict__ gamma, const float* __restrict__ beta,
          float* __restrict__ h, unsigned short* __restrict__ hB, int s) {
  __shared__ unsigned short rha[16 * 128];
  __shared__ float lsum[4][16], lsq[4][16];
  int tid = threadIdx.x;
  int lane = tid & 63;
  int w = tid >> 6;
  int n0 = blockIdx.x * 2;
  int j = w >> 1, half = w & 1;
  int n = n0 + j;
  float dn = dinv[n];
  float acc[8], val[8];
  int foff = half * 512 + lane * 8;
  bf8_to_f(rhB + (size_t)n * (NB * NH) + foff, val);
#pragma unroll
  for (int i = 0; i < 8; i++) acc[i] = dn * val[i];
  int k0 = row_start[n], k1 = row_start[n + 1];
  for (int kb = k0; kb < k1; kb += 64) {
    int m = k1 - kb; if (m > 64) m = 64;
    int idx = 0; float wv = 0.f;
    if (lane < m) { idx = csr_src[kb + lane]; wv = dinv[idx]; }
    for (int k = 0; k < m; k++) {
      int sn = __shfl(idx, k, 64);
      float ww = __shfl(wv, k, 64);
      bf8_to_f(rhB + (size_t)sn * (NB * NH) + foff, val);
#pragma unroll
      for (int i = 0; i < 8; i++) acc[i] = fmaf(ww, val[i], acc[i]);
    }
  }
  {
    int row = j * 8 + (foff >> 7);
    int f = foff & 127;
    unsigned int pk[4];
#pragma unroll
    for (int i = 0; i < 4; i++)
      pk[i] = ((unsigned int)f2bf(dn * acc[2*i+1]) << 16) | f2bf(dn * acc[2*i]);
    int byte = (row * 256 + f * 2) ^ ((row & 7) << 4);
    *(u32x4*)((char*)rha + byte) = *(u32x4*)pk;
  }
  __syncthreads();
  // ---- GEMM rows 16 x cols 128; wave w -> col-tiles 2w, 2w+1
  int ar = lane & 15;
  int koff = (lane >> 4) * 8;
  short8v afr[6];
  const unsigned short* xrow =
      Xa + (((size_t)s * NN + n0 + (ar >> 3)) * NB + (ar & 7)) * ND;
  afr[0] = *(const short8v*)(xrow + koff);
  afr[1] = *(const short8v*)(xrow + 32 + koff);
#pragma unroll
  for (int kb = 2; kb < 6; kb++) {
    int kk = (kb - 2) * 32 + koff;
    int byte = (ar * 256 + kk * 2) ^ ((ar & 7) << 4);
    afr[kb] = *(const short8v*)((char*)rha + byte);
  }
  f32x4 cacc[2];
  cacc[0] = (f32x4){0.f, 0.f, 0.f, 0.f};
  cacc[1] = (f32x4){0.f, 0.f, 0.f, 0.f};
#pragma unroll
  for (int ct = 0; ct < 2; ct++) {
    const unsigned short* wcol = Wt + (size_t)((w * 2 + ct) * 16 + (lane & 15)) * 192;
#pragma unroll
    for (int kb = 0; kb < 6; kb++) {
      short8v bfr = *(const short8v*)(wcol + kb * 32 + koff);
      cacc[ct] = __builtin_amdgcn_mfma_f32_16x16x32_bf16(afr[kb], bfr, cacc[ct], 0, 0, 0);
    }
  }
  // ---- epilogue: tanh, gate, LN over 128 cols
  int r0 = (lane >> 4) * 4;
  float u[2][4];
  float psum[4] = {0.f, 0.f, 0.f, 0.f};
  float psq[4] = {0.f, 0.f, 0.f, 0.f};
#pragma unroll
  for (int ct = 0; ct < 2; ct++) {
    int col = (w * 2 + ct) * 16 + (lane & 15);
    float bcc = bc[col];
#pragma unroll
    for (int q = 0; q < 4; q++) {
      int r = r0 + q;
      size_t gidx = (((size_t)(n0 + (r >> 3))) * NB + (r & 7)) * NH + col;
      float gc = cacc[ct][q] + bcc;
      float ea = __expf(-2.f * fabsf(gc));
      float th = (1.f - ea) / (1.f + ea);
      float cand = copysignf(th, gc);
      float zv = z[gidx];
      float uu = (1.f - zv) * h[gidx] + zv * cand;
      u[ct][q] = uu;
      psum[q] += uu; psq[q] += uu * uu;
    }
  }
#pragma unroll
  for (int q = 0; q < 4; q++) {
    float s1 = psum[q], s2 = psq[q];
#pragma unroll
    for (int o = 1; o <= 8; o <<= 1) {
      s1 += __shfl_xor(s1, o, 64);
      s2 += __shfl_xor(s2, o, 64);
    }
    if ((lane & 15) == 0) {
      lsum[w][r0 + q] = s1; lsq[w][r0 + q] = s2;
    }
  }
  __syncthreads();
#pragma unroll
  for (int ct = 0; ct < 2; ct++) {
    int col = (w * 2 + ct) * 16 + (lane & 15);
    float g = gamma[col], bt = beta[col];
#pragma unroll
    for (int q = 0; q < 4; q++) {
      int r = r0 + q;
      float tot = lsum[0][r] + lsum[1][r] + lsum[2][r] + lsum[3][r];
      float totq = lsq[0][r] + lsq[1][r] + lsq[2][r] + lsq[3][r];
      float mu = tot * (1.f / NH);
      float var = totq * (1.f / NH) - mu * mu;
      float inv = rsqrtf(var + LN_EPS);
      float hv = (u[ct][q] - mu) * inv * g + bt;
      size_t gidx = (((size_t)(n0 + (r >> 3))) * NB + (r & 7)) * NH + col;
      h[gidx] = hv;
      hB[gidx] = f2bf(hv);
    }
  }
}

// ---------------- pool: out[b][f] = mean_n h[n][b][f] ----------------------

__global__ __launch_bounds__(128)
void k_pool(const float* __restrict__ h, float* __restrict__ out) {
  int b = blockIdx.x & 7;
  int c = blockIdx.x >> 3;   // 16 chunks of 128 nodes
  int f = threadIdx.x;
  float acc = 0.f;
  for (int n = c * 128; n < c * 128 + 128; n++)
    acc += h[((size_t)n * NB + b) * NH + f];
  atomicAdd(&out[b * NH + f], acc * (1.f / NN));
}

// ---------------- host ----------------------------------------------------

extern "C" void kernel_launch(void* const* d_in, const int* in_sizes, int n_in,
                              void* d_out, int out_size, void* d_ws, size_t ws_size,
                              hipStream_t stream) {
  const float* x     = (const float*)d_in[0];
  const int*   ei    = (const int*)d_in[1];
  const float* Wz    = (const float*)d_in[3];
  const float* bz    = (const float*)d_in[4];
  const float* Wr    = (const float*)d_in[5];
  const float* br    = (const float*)d_in[6];
  const float* Wc    = (const float*)d_in[7];
  const float* bc    = (const float*)d_in[8];
  const float* gamma = (const float*)d_in[9];
  const float* beta  = (const float*)d_in[10];
  float* out = (float*)d_out;

  char* ws = (char*)d_ws;
  size_t off = 0;
  auto alloc = [&](size_t bytes) {
    void* p = ws + off;
    off = (off + bytes + 255) & ~(size_t)255;
    return p;
  };
  float* h  = (float*)alloc((size_t)NT * NH * 4);          // [n][b][128] fp32
  float* z  = (float*)alloc((size_t)NT * NH * 4);          // [n][b][128] fp32
  unsigned short* hB   = (unsigned short*)alloc((size_t)NT * NH * 2);
  unsigned short* rhB  = (unsigned short*)alloc((size_t)NT * NH * 2);
  unsigned short* xT   = (unsigned short*)alloc((size_t)NS * NN * NB * ND * 2);
  unsigned short* Xa   = (unsigned short*)alloc((size_t)NS * NN * NB * ND * 2);
  unsigned short* Wt_zr = (unsigned short*)alloc((size_t)256 * 192 * 2);
  unsigned short* Wt_c  = (unsigned short*)alloc((size_t)128 * 192 * 2);
  float* dinv = (float*)alloc(NN * 4);
  int* deg       = (int*)alloc(NN * 4);
  int* row_start = (int*)alloc((NN + 1) * 4);
  int* cursor    = (int*)alloc(NN * 4);
  int* csr_src   = (int*)alloc(NE * 4);

  const int* e_src = ei;
  const int* e_dst = ei + NE;

  hipMemsetAsync(h, 0, (size_t)NT * NH * 4, stream);
  hipMemsetAsync(hB, 0, (size_t)NT * NH * 2, stream);
  hipMemsetAsync(deg, 0, NN * 4, stream);
  hipMemsetAsync(cursor, 0, NN * 4, stream);
  hipMemsetAsync(d_out, 0, (size_t)NB * NH * 4, stream);

  k_count<<<NE / 256, 256, 0, stream>>>(e_dst, deg);
  k_scan<<<1, 256, 0, stream>>>(deg, row_start, dinv);
  k_scatter<<<NE / 256, 256, 0, stream>>>(e_src, e_dst, row_start, cursor, csr_src);
  k_wcvt<<<256, 192, 0, stream>>>(Wz, Wr, Wc, Wt_zr, Wt_c);
  k_xT<<<16384, 256, 0, stream>>>(x, xT);
  k_aggX2<<<16384, 256, 0, stream>>>(xT, row_start, csr_src, dinv, Xa);

  for (int s = 0; s < NS; s++) {
    k_zrF<<<NN / 2, 256, 0, stream>>>(Xa, hB, h, Wt_zr, row_start, csr_src, dinv,
                                      bz, br, z, rhB, s);
    k_cF<<<NN / 2, 256, 0, stream>>>(Xa, rhB, z, Wt_c, row_start, csr_src, dinv,
                                     bc, gamma, beta, h, hB, s);
  }
  k_pool<<<128, 128, 0, stream>>>(h, out);
}